// Round 5
// baseline (211.129 us; speedup 1.0000x reference)
//
#include <hip/hip_runtime.h>

// SIREN hypernetwork, round 5.
// siren_pre: unchanged — W_eff = (ws_h+offset)/2pi, f16, chunk layout
//            [n][l][c(8)][e(256)][k(32)]; a wave's MFMA A-fragment load is
//            1 KiB contiguous from global (L2-resident, sample pinned to XCD).
// siren_main: 4096 blocks = 16 samples x 256 tiles of 64 points, 256 threads
//            (4 waves = e-quarters; per wave et=4 x pt=4, acc=64 VGPR).
//            sH = 32 KB, total LDS 39.7 KB -> 4 blocks/CU = 4 independent
//            waves/SIMD (latency hiding; round 4 had 2 and 60% stall).
//            No W staging in LDS; A-fragments straight from L2.

#define N_S 16
#define HW_S 16384
#define E_S 263936
#define INV2PI 0.15915494309189535f
#define OM2PI  4.774648292756860f   // 30/(2pi)

typedef _Float16 f16x8 __attribute__((ext_vector_type(8)));
typedef _Float16 f16x4 __attribute__((ext_vector_type(4)));
typedef _Float16 f16x2 __attribute__((ext_vector_type(2)));
typedef float f32x4 __attribute__((ext_vector_type(4)));

// ws layout (bytes)
#define WT_OFF   0u          // f16 [16][4][8][256][32]  (8388608 B)
#define W0T_OFF  8388608u    // f32 [16][256][2]  * 30/2pi
#define B0_OFF   8421376u    // f32 [16][256]     * 30/2pi
#define BE_OFF   8437760u    // f32 [16][4][256]  * 1/2pi

__device__ __forceinline__ float fsin(float z) {
  return __builtin_amdgcn_sinf(__builtin_amdgcn_fractf(z));
}

__global__ __launch_bounds__(256) void siren_pre(
    const float* __restrict__ wo, const float* __restrict__ w0,
    const float* __restrict__ b0, const float* __restrict__ wsh,
    const float* __restrict__ bsh, char* __restrict__ ws)
{
  __shared__ float tile[64][65];
  int b = blockIdx.x, t = threadIdx.x;
  if (b < 1024) {
    int n = b >> 6, rem = b & 63, l = rem >> 4, sub = rem & 15;
    int tk = sub >> 2, te = sub & 3;
    int e_loc = t & 63, ksub = t >> 6;
    const float* wo_n = wo + (size_t)n * E_S + 768 + l * 65792;
    const float* wsh_l = wsh + l * 65536;
    for (int r = 0; r < 16; ++r) {
      int k_loc = ksub * 16 + r;
      int k = tk * 64 + k_loc, e = te * 64 + e_loc;
      tile[k_loc][e_loc] = (wsh_l[k * 256 + e] + wo_n[k * 256 + e]) * INV2PI;
    }
    __syncthreads();
    _Float16* wtl = (_Float16*)(ws + WT_OFF) + (size_t)(n * 4 + l) * 65536;
    int kp = (t & 31) * 2, esub = t >> 5;
    for (int r = 0; r < 8; ++r) {
      int e_loc2 = esub * 8 + r;
      f16x2 hv;
      hv[0] = (_Float16)tile[kp][e_loc2];
      hv[1] = (_Float16)tile[kp + 1][e_loc2];
      int e = te * 64 + e_loc2, k = tk * 64 + kp;
      int c = k >> 5, kin = k & 31;
      *(f16x2*)(wtl + (size_t)c * 8192 + e * 32 + kin) = hv;
    }
  } else if (b == 1024) {
    float* w0t = (float*)(ws + W0T_OFF);
    float* b0e = (float*)(ws + B0_OFF);
    for (int idx = t; idx < 4096; idx += 256) {
      int n = idx >> 8, e = idx & 255;
      const float* wo_n = wo + (size_t)n * E_S;
      float2 v;
      v.x = (w0[e] + wo_n[e]) * OM2PI;
      v.y = (w0[256 + e] + wo_n[256 + e]) * OM2PI;
      *(float2*)(w0t + (n * 256 + e) * 2) = v;
      b0e[n * 256 + e] = (b0[e] + wo_n[512 + e]) * OM2PI;
    }
  } else {
    float* be = (float*)(ws + BE_OFF);
    for (int idx = t; idx < 16384; idx += 256) {
      int n = idx >> 10, rem = idx & 1023, l = rem >> 8, e = rem & 255;
      be[(n * 4 + l) * 256 + e] =
          (bsh[l * 256 + e] + wo[(size_t)n * E_S + 768 + l * 65792 + 65536 + e]) * INV2PI;
    }
  }
}

__global__ __launch_bounds__(256, 4) void siren_main(
    const float* __restrict__ x, const char* __restrict__ ws,
    const float* __restrict__ w_out, const float* __restrict__ b_out,
    const float* __restrict__ out_scale, float* __restrict__ out)
{
  __shared__ __align__(16) unsigned char sH[32768]; // H[64 p][256 e] f16, row-XOR-swizzled
  __shared__ float sWf[768];         // w_out [256][3]
  __shared__ float sRed[4][64][3];   // per-wave partials
  __shared__ float sFin[192];        // final [64][3]

  int tid = threadIdx.x;
  int lane = tid & 63, eq = tid >> 6;  // wave = e-quarter
  int g = lane >> 4, li = lane & 15;
  int bid = blockIdx.x;
  int n = bid & 15, tile = bid >> 4;   // sample n -> XCD n&7 (L2 locality)

  const char* wt_n = ws + WT_OFF + (size_t)n * 524288;

  // stage w_out once (read only in epilogue)
  for (int i = tid; i < 768; i += 256) sWf[i] = w_out[i];

  // ---- layer 0 in fp32 (weights pre-scaled by 30/2pi) -> sH
  {
    const float* xp = x + ((size_t)n * HW_S + (size_t)tile * 64) * 2;
    int p = tid & 63;
    float2 xv = *(const float2*)(xp + p * 2);
    const float* w0t = (const float*)(ws + W0T_OFF) + n * 512;
    const float* b0e = (const float*)(ws + B0_OFF) + n * 256;
    int swz = (p & 7) << 4;
    unsigned char* hrow = sH + p * 512;
#pragma unroll
    for (int it = 0; it < 8; ++it) {
      int eg = eq * 8 + it;            // wave-uniform
      int e0 = eg * 8;
      f32x4 wa = *(const f32x4*)(w0t + e0 * 2);
      f32x4 wb = *(const f32x4*)(w0t + e0 * 2 + 4);
      f32x4 wc = *(const f32x4*)(w0t + e0 * 2 + 8);
      f32x4 wd = *(const f32x4*)(w0t + e0 * 2 + 12);
      f32x4 ba = *(const f32x4*)(b0e + e0);
      f32x4 bb = *(const f32x4*)(b0e + e0 + 4);
      f16x8 hv;
      hv[0] = (_Float16)fsin(fmaf(xv.y, wa[1], fmaf(xv.x, wa[0], ba[0])));
      hv[1] = (_Float16)fsin(fmaf(xv.y, wa[3], fmaf(xv.x, wa[2], ba[1])));
      hv[2] = (_Float16)fsin(fmaf(xv.y, wb[1], fmaf(xv.x, wb[0], ba[2])));
      hv[3] = (_Float16)fsin(fmaf(xv.y, wb[3], fmaf(xv.x, wb[2], ba[3])));
      hv[4] = (_Float16)fsin(fmaf(xv.y, wc[1], fmaf(xv.x, wc[0], bb[0])));
      hv[5] = (_Float16)fsin(fmaf(xv.y, wc[3], fmaf(xv.x, wc[2], bb[1])));
      hv[6] = (_Float16)fsin(fmaf(xv.y, wd[1], fmaf(xv.x, wd[0], bb[2])));
      hv[7] = (_Float16)fsin(fmaf(xv.y, wd[3], fmaf(xv.x, wd[2], bb[3])));
      *(f16x8*)(hrow + ((eg * 16) ^ swz)) = hv;
    }
  }
  __syncthreads();

  const float* be_n = (const float*)(ws + BE_OFF) + n * 1024;
  int laneoff = (eq * 64 + li) * 64 + g * 16;  // byte offset of lane's W row slice
  f32x4 acc[4][4];

  for (int l = 0; l < 4; ++l) {
    const float* bias = be_n + l * 256;
#pragma unroll
    for (int et = 0; et < 4; ++et) {
      f32x4 bv = *(const f32x4*)(bias + eq * 64 + et * 16 + g * 4);
#pragma unroll
      for (int pt = 0; pt < 4; ++pt) acc[et][pt] = bv;
    }
    const char* wl = wt_n + (size_t)l * 131072 + laneoff;
#pragma unroll
    for (int c = 0; c < 8; ++c) {
      f16x8 afr[4], bfr[4];
#pragma unroll
      for (int et = 0; et < 4; ++et)
        afr[et] = *(const f16x8*)(wl + c * 16384 + et * 1024);
#pragma unroll
      for (int pt = 0; pt < 4; ++pt) {
        int p = pt * 16 + li;
        bfr[pt] = *(const f16x8*)(sH + p * 512 + ((c * 64 + g * 16) ^ ((p & 7) << 4)));
      }
#pragma unroll
      for (int et = 0; et < 4; ++et)
#pragma unroll
        for (int pt = 0; pt < 4; ++pt)
          acc[et][pt] = __builtin_amdgcn_mfma_f32_16x16x32_f16(afr[et], bfr[pt], acc[et][pt], 0, 0, 0);
    }
    if (l < 3) {
      __syncthreads();  // all waves done reading layer-l H
#pragma unroll
      for (int et = 0; et < 4; ++et) {
        int eb = eq * 128 + et * 32 + g * 8;   // byte offset of e*2
#pragma unroll
        for (int pt = 0; pt < 4; ++pt) {
          int p = pt * 16 + li;
          f16x4 hv;
#pragma unroll
          for (int r = 0; r < 4; ++r)
            hv[r] = (_Float16)fsin(acc[et][pt][r]);
          *(f16x4*)(sH + p * 512 + (eb ^ ((p & 7) << 4))) = hv;
        }
      }
      __syncthreads();  // new H visible
    }
  }

  // ---- epilogue: h = sin(acc), out = (h @ w_out + b_out) * out_scale
  float part[4][3];
#pragma unroll
  for (int pt = 0; pt < 4; ++pt)
#pragma unroll
    for (int co = 0; co < 3; ++co) part[pt][co] = 0.f;
#pragma unroll
  for (int et = 0; et < 4; ++et) {
#pragma unroll
    for (int r = 0; r < 4; ++r) {
      int e = eq * 64 + et * 16 + g * 4 + r;
      float wc0 = sWf[e * 3 + 0], wc1 = sWf[e * 3 + 1], wc2 = sWf[e * 3 + 2];
#pragma unroll
      for (int pt = 0; pt < 4; ++pt) {
        float h = fsin(acc[et][pt][r]);
        part[pt][0] = fmaf(h, wc0, part[pt][0]);
        part[pt][1] = fmaf(h, wc1, part[pt][1]);
        part[pt][2] = fmaf(h, wc2, part[pt][2]);
      }
    }
  }
#pragma unroll
  for (int pt = 0; pt < 4; ++pt)
#pragma unroll
    for (int co = 0; co < 3; ++co) {
      float v = part[pt][co];
      v += __shfl_xor(v, 16);
      v += __shfl_xor(v, 32);
      part[pt][co] = v;
    }
  if (g == 0) {
#pragma unroll
    for (int pt = 0; pt < 4; ++pt) {
      int p = pt * 16 + li;
#pragma unroll
      for (int co = 0; co < 3; ++co)
        sRed[eq][p][co] = part[pt][co];
    }
  }
  __syncthreads();
  if (tid < 64) {
    int p = tid;
#pragma unroll
    for (int co = 0; co < 3; ++co)
      sFin[p * 3 + co] = (sRed[0][p][co] + sRed[1][p][co] +
                          sRed[2][p][co] + sRed[3][p][co] +
                          b_out[co]) * out_scale[co];
  }
  __syncthreads();
  float* op = out + ((size_t)n * HW_S + (size_t)tile * 64) * 3;
  if (tid < 192) op[tid] = sFin[tid];
}

extern "C" void kernel_launch(void* const* d_in, const int* in_sizes, int n_in,
                              void* d_out, int out_size, void* d_ws, size_t ws_size,
                              hipStream_t stream) {
  const float* x      = (const float*)d_in[0];
  const float* wo     = (const float*)d_in[1];
  const float* w0     = (const float*)d_in[2];
  const float* b0     = (const float*)d_in[3];
  const float* wsh    = (const float*)d_in[4];
  const float* bsh    = (const float*)d_in[5];
  const float* w_out  = (const float*)d_in[6];
  const float* b_out  = (const float*)d_in[7];
  const float* oscale = (const float*)d_in[8];
  float* out = (float*)d_out;
  char* ws = (char*)d_ws;

  siren_pre<<<1026, 256, 0, stream>>>(wo, w0, b0, wsh, bsh, ws);
  siren_main<<<4096, 256, 0, stream>>>(x, ws, w_out, b_out, oscale, out);
}

// Round 6
// 200.461 us; speedup vs baseline: 1.0532x; 1.0532x over previous
//
#include <hip/hip_runtime.h>

// SIREN hypernetwork, round 6.
// siren_pre: unchanged — W_eff = (ws_h+offset)/2pi, f16, chunk layout
//            [n][l][c(8)][e(256)][k(32)]; wave A-fragment load = 1 KiB
//            contiguous from global (L2-resident, sample pinned to XCD).
// siren_main: 2048 blocks = 16 samples x 128 tiles of 128 points, 256 threads.
//            Wave decomposition (8,4): wave = 128e x 64p (we = e-half,
//            wp = p-half). LDS H-read traffic halves vs round 4 (each wave
//            reads only its 64-p half) -> LDS ~385 cyc/chunk/CU vs MFMA 307.
//            Round 4 was LDS-b128-throughput-bound at MfmaUtil 35/41% ceiling.
//            acc[8][4]=128 VGPR + afr[8]/bfr[4]; launch_bounds(256,2) (the
//            (256,4) of round 5 caused 64-VGPR + 158 MB scratch spill).

#define N_S 16
#define HW_S 16384
#define E_S 263936
#define INV2PI 0.15915494309189535f
#define OM2PI  4.774648292756860f   // 30/(2pi)

typedef _Float16 f16x8 __attribute__((ext_vector_type(8)));
typedef _Float16 f16x4 __attribute__((ext_vector_type(4)));
typedef _Float16 f16x2 __attribute__((ext_vector_type(2)));
typedef float f32x4 __attribute__((ext_vector_type(4)));

// ws layout (bytes)
#define WT_OFF   0u          // f16 [16][4][8][256][32]  (8388608 B)
#define W0T_OFF  8388608u    // f32 [16][256][2]  * 30/2pi
#define B0_OFF   8421376u    // f32 [16][256]     * 30/2pi
#define BE_OFF   8437760u    // f32 [16][4][256]  * 1/2pi

__device__ __forceinline__ float fsin(float z) {
  return __builtin_amdgcn_sinf(__builtin_amdgcn_fractf(z));
}

__global__ __launch_bounds__(256) void siren_pre(
    const float* __restrict__ wo, const float* __restrict__ w0,
    const float* __restrict__ b0, const float* __restrict__ wsh,
    const float* __restrict__ bsh, char* __restrict__ ws)
{
  __shared__ float tile[64][65];
  int b = blockIdx.x, t = threadIdx.x;
  if (b < 1024) {
    int n = b >> 6, rem = b & 63, l = rem >> 4, sub = rem & 15;
    int tk = sub >> 2, te = sub & 3;
    int e_loc = t & 63, ksub = t >> 6;
    const float* wo_n = wo + (size_t)n * E_S + 768 + l * 65792;
    const float* wsh_l = wsh + l * 65536;
    for (int r = 0; r < 16; ++r) {
      int k_loc = ksub * 16 + r;
      int k = tk * 64 + k_loc, e = te * 64 + e_loc;
      tile[k_loc][e_loc] = (wsh_l[k * 256 + e] + wo_n[k * 256 + e]) * INV2PI;
    }
    __syncthreads();
    _Float16* wtl = (_Float16*)(ws + WT_OFF) + (size_t)(n * 4 + l) * 65536;
    int kp = (t & 31) * 2, esub = t >> 5;
    for (int r = 0; r < 8; ++r) {
      int e_loc2 = esub * 8 + r;
      f16x2 hv;
      hv[0] = (_Float16)tile[kp][e_loc2];
      hv[1] = (_Float16)tile[kp + 1][e_loc2];
      int e = te * 64 + e_loc2, k = tk * 64 + kp;
      int c = k >> 5, kin = k & 31;
      *(f16x2*)(wtl + (size_t)c * 8192 + e * 32 + kin) = hv;
    }
  } else if (b == 1024) {
    float* w0t = (float*)(ws + W0T_OFF);
    float* b0e = (float*)(ws + B0_OFF);
    for (int idx = t; idx < 4096; idx += 256) {
      int n = idx >> 8, e = idx & 255;
      const float* wo_n = wo + (size_t)n * E_S;
      float2 v;
      v.x = (w0[e] + wo_n[e]) * OM2PI;
      v.y = (w0[256 + e] + wo_n[256 + e]) * OM2PI;
      *(float2*)(w0t + (n * 256 + e) * 2) = v;
      b0e[n * 256 + e] = (b0[e] + wo_n[512 + e]) * OM2PI;
    }
  } else {
    float* be = (float*)(ws + BE_OFF);
    for (int idx = t; idx < 16384; idx += 256) {
      int n = idx >> 10, rem = idx & 1023, l = rem >> 8, e = rem & 255;
      be[(n * 4 + l) * 256 + e] =
          (bsh[l * 256 + e] + wo[(size_t)n * E_S + 768 + l * 65792 + 65536 + e]) * INV2PI;
    }
  }
}

__global__ __launch_bounds__(256, 2) void siren_main(
    const float* __restrict__ x, const char* __restrict__ ws,
    const float* __restrict__ w_out, const float* __restrict__ b_out,
    const float* __restrict__ out_scale, float* __restrict__ out)
{
  __shared__ __align__(16) unsigned char sH[65536];  // H[128 p][256 e] f16, row-XOR-swizzled
  __shared__ float sWf[768];        // w_out [256][3]
  __shared__ float sRed[2][128][3]; // per-e-half partials
  __shared__ float sFin[384];       // final [128][3]

  int tid = threadIdx.x;
  int lane = tid & 63, wave = tid >> 6;
  int g = lane >> 4, li = lane & 15;
  int we = wave & 1, wp = wave >> 1;   // e-half (128 e), p-half (64 p)
  int bid = blockIdx.x;
  int n = bid & 15, tile = bid >> 4;   // sample n -> XCD n&7 (L2 locality)

  const char* wt_n = ws + WT_OFF + (size_t)n * 524288;

  // stage w_out once (read only in epilogue)
  for (int i = tid; i < 768; i += 256) sWf[i] = w_out[i];

  // ---- layer 0 in fp32 (weights pre-scaled by 30/2pi) -> sH
  {
    const float* xp = x + ((size_t)n * HW_S + (size_t)tile * 128) * 2;
    int p = tid & 127;
    float2 xv = *(const float2*)(xp + p * 2);
    const float* w0t = (const float*)(ws + W0T_OFF) + n * 512;
    const float* b0e = (const float*)(ws + B0_OFF) + n * 256;
    int swz = (p & 7) << 4;
    unsigned char* hrow = sH + p * 512;
#pragma unroll
    for (int it = 0; it < 16; ++it) {
      int eg = (tid >> 7) * 16 + it;   // 0..31, wave-uniform
      int e0 = eg * 8;
      f32x4 wa = *(const f32x4*)(w0t + e0 * 2);
      f32x4 wb = *(const f32x4*)(w0t + e0 * 2 + 4);
      f32x4 wc = *(const f32x4*)(w0t + e0 * 2 + 8);
      f32x4 wd = *(const f32x4*)(w0t + e0 * 2 + 12);
      f32x4 ba = *(const f32x4*)(b0e + e0);
      f32x4 bb = *(const f32x4*)(b0e + e0 + 4);
      f16x8 hv;
      hv[0] = (_Float16)fsin(fmaf(xv.y, wa[1], fmaf(xv.x, wa[0], ba[0])));
      hv[1] = (_Float16)fsin(fmaf(xv.y, wa[3], fmaf(xv.x, wa[2], ba[1])));
      hv[2] = (_Float16)fsin(fmaf(xv.y, wb[1], fmaf(xv.x, wb[0], ba[2])));
      hv[3] = (_Float16)fsin(fmaf(xv.y, wb[3], fmaf(xv.x, wb[2], ba[3])));
      hv[4] = (_Float16)fsin(fmaf(xv.y, wc[1], fmaf(xv.x, wc[0], bb[0])));
      hv[5] = (_Float16)fsin(fmaf(xv.y, wc[3], fmaf(xv.x, wc[2], bb[1])));
      hv[6] = (_Float16)fsin(fmaf(xv.y, wd[1], fmaf(xv.x, wd[0], bb[2])));
      hv[7] = (_Float16)fsin(fmaf(xv.y, wd[3], fmaf(xv.x, wd[2], bb[3])));
      *(f16x8*)(hrow + ((eg * 16) ^ swz)) = hv;
    }
  }
  __syncthreads();

  const float* be_n = (const float*)(ws + BE_OFF) + n * 1024;
  // byte offset of lane's W row slice: e = we*128 + et*16 + li, row = 64 B
  int laneoff = (we * 128 + li) * 64 + g * 16;
  f32x4 acc[8][4];

  for (int l = 0; l < 4; ++l) {
    const float* bias = be_n + l * 256;
#pragma unroll
    for (int et = 0; et < 8; ++et) {
      f32x4 bv = *(const f32x4*)(bias + we * 128 + et * 16 + g * 4);
#pragma unroll
      for (int pt = 0; pt < 4; ++pt) acc[et][pt] = bv;
    }
    const char* wl = wt_n + (size_t)l * 131072 + laneoff;
#pragma unroll
    for (int c = 0; c < 8; ++c) {
      f16x8 afr[8], bfr[4];
#pragma unroll
      for (int et = 0; et < 8; ++et)
        afr[et] = *(const f16x8*)(wl + c * 16384 + et * 1024);
#pragma unroll
      for (int pt = 0; pt < 4; ++pt) {
        int p = wp * 64 + pt * 16 + li;
        bfr[pt] = *(const f16x8*)(sH + p * 512 + ((c * 64 + g * 16) ^ ((p & 7) << 4)));
      }
#pragma unroll
      for (int et = 0; et < 8; ++et)
#pragma unroll
        for (int pt = 0; pt < 4; ++pt)
          acc[et][pt] = __builtin_amdgcn_mfma_f32_16x16x32_f16(afr[et], bfr[pt], acc[et][pt], 0, 0, 0);
    }
    if (l < 3) {
      __syncthreads();  // all waves done reading layer-l H
#pragma unroll
      for (int et = 0; et < 8; ++et) {
        int eb = we * 256 + et * 32 + g * 8;   // byte offset of e*2
#pragma unroll
        for (int pt = 0; pt < 4; ++pt) {
          int p = wp * 64 + pt * 16 + li;
          f16x4 hv;
#pragma unroll
          for (int r = 0; r < 4; ++r)
            hv[r] = (_Float16)fsin(acc[et][pt][r]);
          *(f16x4*)(sH + p * 512 + (eb ^ ((p & 7) << 4))) = hv;
        }
      }
      __syncthreads();  // new H visible
    }
  }

  // ---- epilogue: h = sin(acc), out = (h @ w_out + b_out) * out_scale
  float part[4][3];
#pragma unroll
  for (int pt = 0; pt < 4; ++pt)
#pragma unroll
    for (int co = 0; co < 3; ++co) part[pt][co] = 0.f;
#pragma unroll
  for (int et = 0; et < 8; ++et) {
#pragma unroll
    for (int r = 0; r < 4; ++r) {
      int e = we * 128 + et * 16 + g * 4 + r;
      float wc0 = sWf[e * 3 + 0], wc1 = sWf[e * 3 + 1], wc2 = sWf[e * 3 + 2];
#pragma unroll
      for (int pt = 0; pt < 4; ++pt) {
        float h = fsin(acc[et][pt][r]);
        part[pt][0] = fmaf(h, wc0, part[pt][0]);
        part[pt][1] = fmaf(h, wc1, part[pt][1]);
        part[pt][2] = fmaf(h, wc2, part[pt][2]);
      }
    }
  }
#pragma unroll
  for (int pt = 0; pt < 4; ++pt)
#pragma unroll
    for (int co = 0; co < 3; ++co) {
      float v = part[pt][co];
      v += __shfl_xor(v, 16);
      v += __shfl_xor(v, 32);
      part[pt][co] = v;
    }
  if (g == 0) {
#pragma unroll
    for (int pt = 0; pt < 4; ++pt) {
      int p = wp * 64 + pt * 16 + li;
#pragma unroll
      for (int co = 0; co < 3; ++co)
        sRed[we][p][co] = part[pt][co];
    }
  }
  __syncthreads();
  if (tid < 128) {
    int p = tid;
#pragma unroll
    for (int co = 0; co < 3; ++co)
      sFin[p * 3 + co] = (sRed[0][p][co] + sRed[1][p][co] +
                          b_out[co]) * out_scale[co];
  }
  __syncthreads();
  float* op = out + ((size_t)n * HW_S + (size_t)tile * 128) * 3;
  for (int i = tid; i < 384; i += 256) op[i] = sFin[i];
}

extern "C" void kernel_launch(void* const* d_in, const int* in_sizes, int n_in,
                              void* d_out, int out_size, void* d_ws, size_t ws_size,
                              hipStream_t stream) {
  const float* x      = (const float*)d_in[0];
  const float* wo     = (const float*)d_in[1];
  const float* w0     = (const float*)d_in[2];
  const float* b0     = (const float*)d_in[3];
  const float* wsh    = (const float*)d_in[4];
  const float* bsh    = (const float*)d_in[5];
  const float* w_out  = (const float*)d_in[6];
  const float* b_out  = (const float*)d_in[7];
  const float* oscale = (const float*)d_in[8];
  float* out = (float*)d_out;
  char* ws = (char*)d_ws;

  siren_pre<<<1026, 256, 0, stream>>>(wo, w0, b0, wsh, bsh, ws);
  siren_main<<<2048, 256, 0, stream>>>(x, ws, w_out, b_out, oscale, out);
}

// Round 7
// 180.413 us; speedup vs baseline: 1.1703x; 1.1111x over previous
//
#include <hip/hip_runtime.h>

// SIREN hypernetwork, round 7.
// siren_pre: unchanged — W_eff = (ws_h+offset)/2pi, f16, layout
//            [n][l][c(8)][e(256)][k(32)] (linear in (l,c) -> single running
//            pointer with imm offsets in the main kernel).
// siren_main: 2048 blocks = 16 samples x 128 tiles of 128 points, 256 thr,
//            4 waves = e-quarters (64e x 128p each, redundancy-1 W reads).
//            32x32x16 f16 MFMA: 16 MFMA/chunk/wave (half the issue slots of
//            16x16x32), afr 16 regs -> explicit next-chunk register prefetch,
//            one v_add64 per chunk. bfr ds_reads: 2 base regs + 16-bit DS
//            imm (pt*16384+c*64), swizzle S=(p&3)<<4 with bit-disjoint fields.

#define N_S 16
#define HW_S 16384
#define E_S 263936
#define INV2PI 0.15915494309189535f
#define OM2PI  4.774648292756860f   // 30/(2pi)

typedef _Float16 f16x8 __attribute__((ext_vector_type(8)));
typedef _Float16 f16x4 __attribute__((ext_vector_type(4)));
typedef _Float16 f16x2 __attribute__((ext_vector_type(2)));
typedef float f32x4 __attribute__((ext_vector_type(4)));
typedef float f32x16 __attribute__((ext_vector_type(16)));

// ws layout (bytes)
#define WT_OFF   0u          // f16 [16][4][8][256][32]  (8388608 B)
#define W0T_OFF  8388608u    // f32 [16][256][2]  * 30/2pi
#define B0_OFF   8421376u    // f32 [16][256]     * 30/2pi
#define BE_OFF   8437760u    // f32 [16][4][256]  * 1/2pi

__device__ __forceinline__ float fsin(float z) {
  return __builtin_amdgcn_sinf(__builtin_amdgcn_fractf(z));
}

__global__ __launch_bounds__(256) void siren_pre(
    const float* __restrict__ wo, const float* __restrict__ w0,
    const float* __restrict__ b0, const float* __restrict__ wsh,
    const float* __restrict__ bsh, char* __restrict__ ws)
{
  __shared__ float tile[64][65];
  int b = blockIdx.x, t = threadIdx.x;
  if (b < 1024) {
    int n = b >> 6, rem = b & 63, l = rem >> 4, sub = rem & 15;
    int tk = sub >> 2, te = sub & 3;
    int e_loc = t & 63, ksub = t >> 6;
    const float* wo_n = wo + (size_t)n * E_S + 768 + l * 65792;
    const float* wsh_l = wsh + l * 65536;
    for (int r = 0; r < 16; ++r) {
      int k_loc = ksub * 16 + r;
      int k = tk * 64 + k_loc, e = te * 64 + e_loc;
      tile[k_loc][e_loc] = (wsh_l[k * 256 + e] + wo_n[k * 256 + e]) * INV2PI;
    }
    __syncthreads();
    _Float16* wtl = (_Float16*)(ws + WT_OFF) + (size_t)(n * 4 + l) * 65536;
    int kp = (t & 31) * 2, esub = t >> 5;
    for (int r = 0; r < 8; ++r) {
      int e_loc2 = esub * 8 + r;
      f16x2 hv;
      hv[0] = (_Float16)tile[kp][e_loc2];
      hv[1] = (_Float16)tile[kp + 1][e_loc2];
      int e = te * 64 + e_loc2, k = tk * 64 + kp;
      int c = k >> 5, kin = k & 31;
      *(f16x2*)(wtl + (size_t)c * 8192 + e * 32 + kin) = hv;
    }
  } else if (b == 1024) {
    float* w0t = (float*)(ws + W0T_OFF);
    float* b0e = (float*)(ws + B0_OFF);
    for (int idx = t; idx < 4096; idx += 256) {
      int n = idx >> 8, e = idx & 255;
      const float* wo_n = wo + (size_t)n * E_S;
      float2 v;
      v.x = (w0[e] + wo_n[e]) * OM2PI;
      v.y = (w0[256 + e] + wo_n[256 + e]) * OM2PI;
      *(float2*)(w0t + (n * 256 + e) * 2) = v;
      b0e[n * 256 + e] = (b0[e] + wo_n[512 + e]) * OM2PI;
    }
  } else {
    float* be = (float*)(ws + BE_OFF);
    for (int idx = t; idx < 16384; idx += 256) {
      int n = idx >> 10, rem = idx & 1023, l = rem >> 8, e = rem & 255;
      be[(n * 4 + l) * 256 + e] =
          (bsh[l * 256 + e] + wo[(size_t)n * E_S + 768 + l * 65792 + 65536 + e]) * INV2PI;
    }
  }
}

__global__ __launch_bounds__(256, 2) void siren_main(
    const float* __restrict__ x, const char* __restrict__ ws,
    const float* __restrict__ w_out, const float* __restrict__ b_out,
    const float* __restrict__ out_scale, float* __restrict__ out)
{
  __shared__ __align__(16) unsigned char sH[65536];  // H[128 p][256 e] f16, S=(p&3)<<4 swizzle
  __shared__ float sWf[768];        // w_out [256][3]
  __shared__ float sRed[4][128][3]; // per-wave partials
  __shared__ float sFin[384];       // final [128][3]

  int tid = threadIdx.x;
  int lane = tid & 63, eq = tid >> 6;  // wave = e-quarter (64 e x 128 p)
  int l31 = lane & 31, lh = lane >> 5; // 32x32 fragment row / k-half-of-8
  int bid = blockIdx.x;
  int n = bid & 15, tile = bid >> 4;   // sample n -> XCD n&7 (L2 locality)

  const char* wt_n = ws + WT_OFF + (size_t)n * 524288;

  // stage w_out once (read only in epilogue)
  for (int i = tid; i < 768; i += 256) sWf[i] = w_out[i];

  // ---- layer 0 in fp32 (weights pre-scaled by 30/2pi) -> sH
  {
    const float* xp = x + ((size_t)n * HW_S + (size_t)tile * 128) * 2;
    int p = tid & 127;
    float2 xv = *(const float2*)(xp + p * 2);
    const float* w0t = (const float*)(ws + W0T_OFF) + n * 512;
    const float* b0e = (const float*)(ws + B0_OFF) + n * 256;
    int swz = (p & 3) << 4;
    unsigned char* hrow = sH + p * 512;
#pragma unroll
    for (int it = 0; it < 16; ++it) {
      int eg = (tid >> 7) * 16 + it;   // 0..31, wave-uniform
      int e0 = eg * 8;
      f32x4 wa = *(const f32x4*)(w0t + e0 * 2);
      f32x4 wb = *(const f32x4*)(w0t + e0 * 2 + 4);
      f32x4 wc = *(const f32x4*)(w0t + e0 * 2 + 8);
      f32x4 wd = *(const f32x4*)(w0t + e0 * 2 + 12);
      f32x4 ba = *(const f32x4*)(b0e + e0);
      f32x4 bb = *(const f32x4*)(b0e + e0 + 4);
      f16x8 hv;
      hv[0] = (_Float16)fsin(fmaf(xv.y, wa[1], fmaf(xv.x, wa[0], ba[0])));
      hv[1] = (_Float16)fsin(fmaf(xv.y, wa[3], fmaf(xv.x, wa[2], ba[1])));
      hv[2] = (_Float16)fsin(fmaf(xv.y, wb[1], fmaf(xv.x, wb[0], ba[2])));
      hv[3] = (_Float16)fsin(fmaf(xv.y, wb[3], fmaf(xv.x, wb[2], ba[3])));
      hv[4] = (_Float16)fsin(fmaf(xv.y, wc[1], fmaf(xv.x, wc[0], bb[0])));
      hv[5] = (_Float16)fsin(fmaf(xv.y, wc[3], fmaf(xv.x, wc[2], bb[1])));
      hv[6] = (_Float16)fsin(fmaf(xv.y, wd[1], fmaf(xv.x, wd[0], bb[2])));
      hv[7] = (_Float16)fsin(fmaf(xv.y, wd[3], fmaf(xv.x, wd[2], bb[3])));
      *(f16x8*)(hrow + ((eg * 16) ^ swz)) = hv;
    }
  }
  __syncthreads();

  const float* be_n = (const float*)(ws + BE_OFF) + n * 1024;

  // afr lane base: e = eq*64 + et*32 + l31, byte = e*64 + lh*16 (+ et*2048 + kh*32 imm)
  const unsigned char* wp =
      (const unsigned char*)wt_n + (eq * 64 + l31) * 64 + lh * 16;

  // bfr lane bases (kh = 0/1): addr = pt*16384 + c*64 (imm) + base
  //   base = l31*512 + ((lh<<4) ^ ((lane&1)<<4)) + ((kh<<5) ^ ((lane&2)<<4))
  int t4 = ((lh ^ (lane & 1)) << 4);
  const unsigned char* hb0 = sH + l31 * 512 + t4 + ((0 ^ ((lane >> 1) & 1)) << 5);
  const unsigned char* hb1 = sH + l31 * 512 + t4 + ((1 ^ ((lane >> 1) & 1)) << 5);

  // H-write lane base: p-row via pt imm; e-byte F = eq*128+et*64+(q*16^S)+lh*8
  int S = (lane & 3) << 4;
  int wbase = l31 * 512 + eq * 128 + lh * 8;

  f32x16 acc[2][4];
  f16x8 a0, a1, a2, a3, n0, n1, n2, n3;
  a0 = *(const f16x8*)(wp + 0);
  a1 = *(const f16x8*)(wp + 32);
  a2 = *(const f16x8*)(wp + 2048);
  a3 = *(const f16x8*)(wp + 2080);

  for (int l = 0; l < 4; ++l) {
    // bias -> acc: e = eq*64 + et*32 + q*8 + lh*4 + j (j=0..3), reg = q*4+j
    const float* bias = be_n + l * 256 + eq * 64 + lh * 4;
#pragma unroll
    for (int et = 0; et < 2; ++et) {
#pragma unroll
      for (int q = 0; q < 4; ++q) {
        f32x4 bv = *(const f32x4*)(bias + et * 32 + q * 8);
#pragma unroll
        for (int j = 0; j < 4; ++j) {
#pragma unroll
          for (int pt = 0; pt < 4; ++pt) acc[et][pt][q * 4 + j] = bv[j];
        }
      }
    }
#pragma unroll
    for (int c = 0; c < 8; ++c) {
      if (c < 7 || l < 3) {  // prefetch next chunk (linear across layers)
        wp += 16384;
        n0 = *(const f16x8*)(wp + 0);
        n1 = *(const f16x8*)(wp + 32);
        n2 = *(const f16x8*)(wp + 2048);
        n3 = *(const f16x8*)(wp + 2080);
      }
      f16x8 b0f[4], b1f[4];
#pragma unroll
      for (int pt = 0; pt < 4; ++pt) {
        b0f[pt] = *(const f16x8*)(hb0 + pt * 16384 + c * 64);
        b1f[pt] = *(const f16x8*)(hb1 + pt * 16384 + c * 64);
      }
#pragma unroll
      for (int pt = 0; pt < 4; ++pt) {
        acc[0][pt] = __builtin_amdgcn_mfma_f32_32x32x16_f16(a0, b0f[pt], acc[0][pt], 0, 0, 0);
        acc[0][pt] = __builtin_amdgcn_mfma_f32_32x32x16_f16(a1, b1f[pt], acc[0][pt], 0, 0, 0);
        acc[1][pt] = __builtin_amdgcn_mfma_f32_32x32x16_f16(a2, b0f[pt], acc[1][pt], 0, 0, 0);
        acc[1][pt] = __builtin_amdgcn_mfma_f32_32x32x16_f16(a3, b1f[pt], acc[1][pt], 0, 0, 0);
      }
      a0 = n0; a1 = n1; a2 = n2; a3 = n3;
    }
    if (l < 3) {
      __syncthreads();  // all waves done reading layer-l H
#pragma unroll
      for (int et = 0; et < 2; ++et) {
#pragma unroll
        for (int q = 0; q < 4; ++q) {
          int off = wbase + et * 64 + ((q * 16) ^ S);
#pragma unroll
          for (int pt = 0; pt < 4; ++pt) {
            f16x4 hv;
#pragma unroll
            for (int j = 0; j < 4; ++j)
              hv[j] = (_Float16)fsin(acc[et][pt][q * 4 + j]);
            *(f16x4*)(sH + pt * 16384 + off) = hv;
          }
        }
      }
      __syncthreads();  // new H visible
    }
  }

  // ---- epilogue: h = sin(acc), out = (h @ w_out + b_out) * out_scale
  float part[4][3];
#pragma unroll
  for (int pt = 0; pt < 4; ++pt)
#pragma unroll
    for (int co = 0; co < 3; ++co) part[pt][co] = 0.f;
#pragma unroll
  for (int et = 0; et < 2; ++et) {
#pragma unroll
    for (int q = 0; q < 4; ++q) {
#pragma unroll
      for (int j = 0; j < 4; ++j) {
        int e = eq * 64 + et * 32 + q * 8 + lh * 4 + j;
        float wc0 = sWf[e * 3 + 0], wc1 = sWf[e * 3 + 1], wc2 = sWf[e * 3 + 2];
#pragma unroll
        for (int pt = 0; pt < 4; ++pt) {
          float h = fsin(acc[et][pt][q * 4 + j]);
          part[pt][0] = fmaf(h, wc0, part[pt][0]);
          part[pt][1] = fmaf(h, wc1, part[pt][1]);
          part[pt][2] = fmaf(h, wc2, part[pt][2]);
        }
      }
    }
  }
#pragma unroll
  for (int pt = 0; pt < 4; ++pt)
#pragma unroll
    for (int co = 0; co < 3; ++co)
      part[pt][co] += __shfl_xor(part[pt][co], 32);
  if (lane < 32) {
#pragma unroll
    for (int pt = 0; pt < 4; ++pt) {
      int p = pt * 32 + l31;
#pragma unroll
      for (int co = 0; co < 3; ++co)
        sRed[eq][p][co] = part[pt][co];
    }
  }
  __syncthreads();
  if (tid < 128) {
    int p = tid;
#pragma unroll
    for (int co = 0; co < 3; ++co)
      sFin[p * 3 + co] = (sRed[0][p][co] + sRed[1][p][co] +
                          sRed[2][p][co] + sRed[3][p][co] +
                          b_out[co]) * out_scale[co];
  }
  __syncthreads();
  float* op = out + ((size_t)n * HW_S + (size_t)tile * 128) * 3;
  for (int i = tid; i < 384; i += 256) op[i] = sFin[i];
}

extern "C" void kernel_launch(void* const* d_in, const int* in_sizes, int n_in,
                              void* d_out, int out_size, void* d_ws, size_t ws_size,
                              hipStream_t stream) {
  const float* x      = (const float*)d_in[0];
  const float* wo     = (const float*)d_in[1];
  const float* w0     = (const float*)d_in[2];
  const float* b0     = (const float*)d_in[3];
  const float* wsh    = (const float*)d_in[4];
  const float* bsh    = (const float*)d_in[5];
  const float* w_out  = (const float*)d_in[6];
  const float* b_out  = (const float*)d_in[7];
  const float* oscale = (const float*)d_in[8];
  float* out = (float*)d_out;
  char* ws = (char*)d_ws;

  siren_pre<<<1026, 256, 0, stream>>>(wo, w0, b0, wsh, bsh, ws);
  siren_main<<<2048, 256, 0, stream>>>(x, ws, w_out, b_out, oscale, out);
}

// Round 8
// 174.816 us; speedup vs baseline: 1.2077x; 1.0320x over previous
//
#include <hip/hip_runtime.h>

// SIREN hypernetwork, round 8 = round 7 + full 3-bit LDS swizzle fix.
// siren_pre: unchanged — W_eff = (ws_h+offset)/2pi, f16, layout
//            [n][l][c(8)][e(256)][k(32)] (linear in (l,c) -> single running
//            pointer with imm offsets in the main kernel).
// siren_main: 2048 blocks = 16 samples x 128 tiles of 128 points, 256 thr,
//            4 waves = e-quarters (64e x 128p each, redundancy-1 W reads).
//            32x32x16 f16 MFMA, register W prefetch. sH swizzle: 16B slot
//            index XOR (p&7)  ->  a wave's b128 reads cover all 32 banks
//            (round 7 XORed only 2 bits -> 16 banks -> 35.6M conflicts).

#define N_S 16
#define HW_S 16384
#define E_S 263936
#define INV2PI 0.15915494309189535f
#define OM2PI  4.774648292756860f   // 30/(2pi)

typedef _Float16 f16x8 __attribute__((ext_vector_type(8)));
typedef _Float16 f16x4 __attribute__((ext_vector_type(4)));
typedef _Float16 f16x2 __attribute__((ext_vector_type(2)));
typedef float f32x4 __attribute__((ext_vector_type(4)));
typedef float f32x16 __attribute__((ext_vector_type(16)));

// ws layout (bytes)
#define WT_OFF   0u          // f16 [16][4][8][256][32]  (8388608 B)
#define W0T_OFF  8388608u    // f32 [16][256][2]  * 30/2pi
#define B0_OFF   8421376u    // f32 [16][256]     * 30/2pi
#define BE_OFF   8437760u    // f32 [16][4][256]  * 1/2pi

__device__ __forceinline__ float fsin(float z) {
  return __builtin_amdgcn_sinf(__builtin_amdgcn_fractf(z));
}

__global__ __launch_bounds__(256) void siren_pre(
    const float* __restrict__ wo, const float* __restrict__ w0,
    const float* __restrict__ b0, const float* __restrict__ wsh,
    const float* __restrict__ bsh, char* __restrict__ ws)
{
  __shared__ float tile[64][65];
  int b = blockIdx.x, t = threadIdx.x;
  if (b < 1024) {
    int n = b >> 6, rem = b & 63, l = rem >> 4, sub = rem & 15;
    int tk = sub >> 2, te = sub & 3;
    int e_loc = t & 63, ksub = t >> 6;
    const float* wo_n = wo + (size_t)n * E_S + 768 + l * 65792;
    const float* wsh_l = wsh + l * 65536;
    for (int r = 0; r < 16; ++r) {
      int k_loc = ksub * 16 + r;
      int k = tk * 64 + k_loc, e = te * 64 + e_loc;
      tile[k_loc][e_loc] = (wsh_l[k * 256 + e] + wo_n[k * 256 + e]) * INV2PI;
    }
    __syncthreads();
    _Float16* wtl = (_Float16*)(ws + WT_OFF) + (size_t)(n * 4 + l) * 65536;
    int kp = (t & 31) * 2, esub = t >> 5;
    for (int r = 0; r < 8; ++r) {
      int e_loc2 = esub * 8 + r;
      f16x2 hv;
      hv[0] = (_Float16)tile[kp][e_loc2];
      hv[1] = (_Float16)tile[kp + 1][e_loc2];
      int e = te * 64 + e_loc2, k = tk * 64 + kp;
      int c = k >> 5, kin = k & 31;
      *(f16x2*)(wtl + (size_t)c * 8192 + e * 32 + kin) = hv;
    }
  } else if (b == 1024) {
    float* w0t = (float*)(ws + W0T_OFF);
    float* b0e = (float*)(ws + B0_OFF);
    for (int idx = t; idx < 4096; idx += 256) {
      int n = idx >> 8, e = idx & 255;
      const float* wo_n = wo + (size_t)n * E_S;
      float2 v;
      v.x = (w0[e] + wo_n[e]) * OM2PI;
      v.y = (w0[256 + e] + wo_n[256 + e]) * OM2PI;
      *(float2*)(w0t + (n * 256 + e) * 2) = v;
      b0e[n * 256 + e] = (b0[e] + wo_n[512 + e]) * OM2PI;
    }
  } else {
    float* be = (float*)(ws + BE_OFF);
    for (int idx = t; idx < 16384; idx += 256) {
      int n = idx >> 10, rem = idx & 1023, l = rem >> 8, e = rem & 255;
      be[(n * 4 + l) * 256 + e] =
          (bsh[l * 256 + e] + wo[(size_t)n * E_S + 768 + l * 65792 + 65536 + e]) * INV2PI;
    }
  }
}

__global__ __launch_bounds__(256, 2) void siren_main(
    const float* __restrict__ x, const char* __restrict__ ws,
    const float* __restrict__ w_out, const float* __restrict__ b_out,
    const float* __restrict__ out_scale, float* __restrict__ out)
{
  __shared__ __align__(16) unsigned char sH[65536];  // H[128 p][256 e] f16, slot^(p&7) swizzle
  __shared__ float sWf[768];        // w_out [256][3]
  __shared__ float sRed[4][128][3]; // per-wave partials
  __shared__ float sFin[384];       // final [128][3]

  int tid = threadIdx.x;
  int lane = tid & 63, eq = tid >> 6;  // wave = e-quarter (64 e x 128 p)
  int l31 = lane & 31, lh = lane >> 5; // 32x32 fragment row / k-half
  int l317 = l31 & 7;
  int bid = blockIdx.x;
  int n = bid & 15, tile = bid >> 4;   // sample n -> XCD n&7 (L2 locality)

  const char* wt_n = ws + WT_OFF + (size_t)n * 524288;

  // stage w_out once (read only in epilogue)
  for (int i = tid; i < 768; i += 256) sWf[i] = w_out[i];

  // ---- layer 0 in fp32 (weights pre-scaled by 30/2pi) -> sH
  {
    const float* xp = x + ((size_t)n * HW_S + (size_t)tile * 128) * 2;
    int p = tid & 127;
    float2 xv = *(const float2*)(xp + p * 2);
    const float* w0t = (const float*)(ws + W0T_OFF) + n * 512;
    const float* b0e = (const float*)(ws + B0_OFF) + n * 256;
    int swz = (p & 7) << 4;
    unsigned char* hrow = sH + p * 512;
#pragma unroll
    for (int it = 0; it < 16; ++it) {
      int eg = (tid >> 7) * 16 + it;   // 0..31, wave-uniform
      int e0 = eg * 8;
      f32x4 wa = *(const f32x4*)(w0t + e0 * 2);
      f32x4 wb = *(const f32x4*)(w0t + e0 * 2 + 4);
      f32x4 wc = *(const f32x4*)(w0t + e0 * 2 + 8);
      f32x4 wd = *(const f32x4*)(w0t + e0 * 2 + 12);
      f32x4 ba = *(const f32x4*)(b0e + e0);
      f32x4 bb = *(const f32x4*)(b0e + e0 + 4);
      f16x8 hv;
      hv[0] = (_Float16)fsin(fmaf(xv.y, wa[1], fmaf(xv.x, wa[0], ba[0])));
      hv[1] = (_Float16)fsin(fmaf(xv.y, wa[3], fmaf(xv.x, wa[2], ba[1])));
      hv[2] = (_Float16)fsin(fmaf(xv.y, wb[1], fmaf(xv.x, wb[0], ba[2])));
      hv[3] = (_Float16)fsin(fmaf(xv.y, wb[3], fmaf(xv.x, wb[2], ba[3])));
      hv[4] = (_Float16)fsin(fmaf(xv.y, wc[1], fmaf(xv.x, wc[0], bb[0])));
      hv[5] = (_Float16)fsin(fmaf(xv.y, wc[3], fmaf(xv.x, wc[2], bb[1])));
      hv[6] = (_Float16)fsin(fmaf(xv.y, wd[1], fmaf(xv.x, wd[0], bb[2])));
      hv[7] = (_Float16)fsin(fmaf(xv.y, wd[3], fmaf(xv.x, wd[2], bb[3])));
      *(f16x8*)(hrow + ((eg * 16) ^ swz)) = hv;
    }
  }
  __syncthreads();

  const float* be_n = (const float*)(ws + BE_OFF) + n * 1024;

  // afr lane base: e = eq*64 + et*32 + l31, byte = e*64 + lh*16 (+ et*2048 + kh*32 imm)
  const unsigned char* wp =
      (const unsigned char*)wt_n + (eq * 64 + l31) * 64 + lh * 16;

  // bfr lane base (slot-swizzled rows): row l31 (+ pt*32 via imm)
  const unsigned char* hbase = sH + l31 * 512;

  f32x16 acc[2][4];
  f16x8 a0, a1, a2, a3, n0, n1, n2, n3;
  a0 = *(const f16x8*)(wp + 0);
  a1 = *(const f16x8*)(wp + 32);
  a2 = *(const f16x8*)(wp + 2048);
  a3 = *(const f16x8*)(wp + 2080);

  for (int l = 0; l < 4; ++l) {
    // bias -> acc: e = eq*64 + et*32 + q*8 + lh*4 + j (j=0..3), reg = q*4+j
    const float* bias = be_n + l * 256 + eq * 64 + lh * 4;
#pragma unroll
    for (int et = 0; et < 2; ++et) {
#pragma unroll
      for (int q = 0; q < 4; ++q) {
        f32x4 bv = *(const f32x4*)(bias + et * 32 + q * 8);
#pragma unroll
        for (int j = 0; j < 4; ++j) {
#pragma unroll
          for (int pt = 0; pt < 4; ++pt) acc[et][pt][q * 4 + j] = bv[j];
        }
      }
    }
#pragma unroll
    for (int c = 0; c < 8; ++c) {
      if (c < 7 || l < 3) {  // prefetch next chunk (linear across layers)
        wp += 16384;
        n0 = *(const f16x8*)(wp + 0);
        n1 = *(const f16x8*)(wp + 32);
        n2 = *(const f16x8*)(wp + 2048);
        n3 = *(const f16x8*)(wp + 2080);
      }
      // slot index = c*4 + kh*2 + lh, stored at slot ^ (l31&7)
      int s0 = (((c * 4 + 0) | lh) ^ l317) << 4;
      int s1 = (((c * 4 + 2) | lh) ^ l317) << 4;
      f16x8 b0f[4], b1f[4];
#pragma unroll
      for (int pt = 0; pt < 4; ++pt) {
        b0f[pt] = *(const f16x8*)(hbase + pt * 16384 + s0);
        b1f[pt] = *(const f16x8*)(hbase + pt * 16384 + s1);
      }
#pragma unroll
      for (int pt = 0; pt < 4; ++pt) {
        acc[0][pt] = __builtin_amdgcn_mfma_f32_32x32x16_f16(a0, b0f[pt], acc[0][pt], 0, 0, 0);
        acc[0][pt] = __builtin_amdgcn_mfma_f32_32x32x16_f16(a1, b1f[pt], acc[0][pt], 0, 0, 0);
        acc[1][pt] = __builtin_amdgcn_mfma_f32_32x32x16_f16(a2, b0f[pt], acc[1][pt], 0, 0, 0);
        acc[1][pt] = __builtin_amdgcn_mfma_f32_32x32x16_f16(a3, b1f[pt], acc[1][pt], 0, 0, 0);
      }
      a0 = n0; a1 = n1; a2 = n2; a3 = n3;
    }
    if (l < 3) {
      __syncthreads();  // all waves done reading layer-l H
      unsigned char* wrow = sH + l31 * 512 + lh * 8;
#pragma unroll
      for (int et = 0; et < 2; ++et) {
#pragma unroll
        for (int q = 0; q < 4; ++q) {
          int so = ((eq * 8 + et * 4 + q) ^ l317) << 4;
#pragma unroll
          for (int pt = 0; pt < 4; ++pt) {
            f16x4 hv;
#pragma unroll
            for (int j = 0; j < 4; ++j)
              hv[j] = (_Float16)fsin(acc[et][pt][q * 4 + j]);
            *(f16x4*)(wrow + pt * 16384 + so) = hv;
          }
        }
      }
      __syncthreads();  // new H visible
    }
  }

  // ---- epilogue: h = sin(acc), out = (h @ w_out + b_out) * out_scale
  float part[4][3];
#pragma unroll
  for (int pt = 0; pt < 4; ++pt)
#pragma unroll
    for (int co = 0; co < 3; ++co) part[pt][co] = 0.f;
#pragma unroll
  for (int et = 0; et < 2; ++et) {
#pragma unroll
    for (int q = 0; q < 4; ++q) {
#pragma unroll
      for (int j = 0; j < 4; ++j) {
        int e = eq * 64 + et * 32 + q * 8 + lh * 4 + j;
        float wc0 = sWf[e * 3 + 0], wc1 = sWf[e * 3 + 1], wc2 = sWf[e * 3 + 2];
#pragma unroll
        for (int pt = 0; pt < 4; ++pt) {
          float h = fsin(acc[et][pt][q * 4 + j]);
          part[pt][0] = fmaf(h, wc0, part[pt][0]);
          part[pt][1] = fmaf(h, wc1, part[pt][1]);
          part[pt][2] = fmaf(h, wc2, part[pt][2]);
        }
      }
    }
  }
#pragma unroll
  for (int pt = 0; pt < 4; ++pt)
#pragma unroll
    for (int co = 0; co < 3; ++co)
      part[pt][co] += __shfl_xor(part[pt][co], 32);
  if (lane < 32) {
#pragma unroll
    for (int pt = 0; pt < 4; ++pt) {
      int p = pt * 32 + l31;
#pragma unroll
      for (int co = 0; co < 3; ++co)
        sRed[eq][p][co] = part[pt][co];
    }
  }
  __syncthreads();
  if (tid < 128) {
    int p = tid;
#pragma unroll
    for (int co = 0; co < 3; ++co)
      sFin[p * 3 + co] = (sRed[0][p][co] + sRed[1][p][co] +
                          sRed[2][p][co] + sRed[3][p][co] +
                          b_out[co]) * out_scale[co];
  }
  __syncthreads();
  float* op = out + ((size_t)n * HW_S + (size_t)tile * 128) * 3;
  for (int i = tid; i < 384; i += 256) op[i] = sFin[i];
}

extern "C" void kernel_launch(void* const* d_in, const int* in_sizes, int n_in,
                              void* d_out, int out_size, void* d_ws, size_t ws_size,
                              hipStream_t stream) {
  const float* x      = (const float*)d_in[0];
  const float* wo     = (const float*)d_in[1];
  const float* w0     = (const float*)d_in[2];
  const float* b0     = (const float*)d_in[3];
  const float* wsh    = (const float*)d_in[4];
  const float* bsh    = (const float*)d_in[5];
  const float* w_out  = (const float*)d_in[6];
  const float* b_out  = (const float*)d_in[7];
  const float* oscale = (const float*)d_in[8];
  float* out = (float*)d_out;
  char* ws = (char*)d_ws;

  siren_pre<<<1026, 256, 0, stream>>>(wo, w0, b0, wsh, bsh, ws);
  siren_main<<<2048, 256, 0, stream>>>(x, ws, w_out, b_out, oscale, out);
}